// Round 5
// baseline (609.250 us; speedup 1.0000x reference)
//
#include <hip/hip_runtime.h>
#include <stdint.h>

typedef unsigned short ushort_t;
typedef __attribute__((ext_vector_type(8))) short bfrag;   // 8 x bf16 (bit pattern)
typedef __attribute__((ext_vector_type(4))) float ffrag;   // mfma f32x4 acc

#define B_  32
#define K_  8
#define N_  4096
#define D_  256
#define H_  4
#define DH_ 64

__device__ __forceinline__ ushort_t f2bf(float f) {
  unsigned int u = __builtin_bit_cast(unsigned int, f);
  u += 0x7FFFu + ((u >> 16) & 1u);           // round-nearest-even
  return (ushort_t)(u >> 16);
}

__device__ __forceinline__ void gload_lds16(const void* g, void* l) {
  __builtin_amdgcn_global_load_lds((const __attribute__((address_space(1))) unsigned int*)g,
                                   (__attribute__((address_space(3))) unsigned int*)l,
                                   16, 0, 0);
}

// ---------------- prep: wkv' = ln_w * [Wk;Wv] (bf16), c1=rowsum(wkv'), c2=rowdot(ln_b, W) ----------------
__global__ __launch_bounds__(256) void k_prep_wkv(const float* __restrict__ Wk, const float* __restrict__ Wv,
                                                  const float* __restrict__ lnw, const float* __restrict__ lnb,
                                                  ushort_t* __restrict__ wkv,
                                                  float* __restrict__ c1, float* __restrict__ c2) {
  int n = blockIdx.x;           // 0..511
  int i = threadIdx.x;          // 0..255
  float wv = (n < 256) ? Wk[n*256 + i] : Wv[(n-256)*256 + i];
  float wp = lnw[i] * wv;
  wkv[n*256 + i] = f2bf(wp);
  float p1 = wp, p2 = lnb[i] * wv;
  #pragma unroll
  for (int off = 32; off >= 1; off >>= 1) { p1 += __shfl_xor(p1, off); p2 += __shfl_xor(p2, off); }
  __shared__ float r1[4], r2[4];
  int w = threadIdx.x >> 6;
  if ((threadIdx.x & 63) == 0) { r1[w] = p1; r2[w] = p2; }
  __syncthreads();
  if (threadIdx.x == 0) { c1[n] = r1[0]+r1[1]+r1[2]+r1[3]; c2[n] = r2[0]+r2[1]+r2[2]+r2[3]; }
}

// ---------------- prep: Wfused = Wih @ Wo  ([768,256]) ----------------
__global__ __launch_bounds__(256) void k_prep_wf(const float* __restrict__ Wih, const float* __restrict__ Wo,
                                                 float* __restrict__ Wf) {
  int j = blockIdx.x;   // 0..767
  int i = threadIdx.x;  // 0..255
  __shared__ float row[256];
  row[i] = Wih[j*256 + i];
  __syncthreads();
  float acc = 0.f;
  #pragma unroll 8
  for (int t = 0; t < 256; ++t) acc += row[t] * Wo[t*256 + i];
  Wf[j*256 + i] = acc;
}

// ---------------- helpers: 8-row LN + 8-slot q projection (used by k_init) ----------------
__device__ __forceinline__ void row_ln_256(float (*S)[256], float (*L)[256],
                                           const float* __restrict__ w, const float* __restrict__ b, int t) {
  int k = t >> 5, ln = t & 31;
  float s = 0.f, q = 0.f;
  #pragma unroll
  for (int j = 0; j < 8; ++j) { float v = S[k][ln + j*32]; s += v; q += v*v; }
  #pragma unroll
  for (int off = 16; off >= 1; off >>= 1) { s += __shfl_xor(s, off); q += __shfl_xor(q, off); }
  float m = s * (1.f/256.f);
  float rstd = rsqrtf(q * (1.f/256.f) - m*m + 1e-5f);
  #pragma unroll
  for (int j = 0; j < 8; ++j) {
    int c = ln + j*32;
    L[k][c] = (S[k][c] - m) * rstd * w[c] + b[c];
  }
}

__device__ __forceinline__ void qproj(float (*L)[256], const float* __restrict__ Wq,
                                      ushort_t* __restrict__ qbuf, int b, int t) {
  int c = t;
  const float4* Wrow = (const float4*)(Wq + (size_t)c * 256);
  float acc[8];
  #pragma unroll
  for (int k = 0; k < 8; ++k) acc[k] = 0.f;
  for (int i = 0; i < 64; ++i) {
    float4 wv = Wrow[i];
    #pragma unroll
    for (int k = 0; k < 8; ++k) {
      float4 xv = *((const float4*)&L[k][0] + i);
      acc[k] = fmaf(xv.x, wv.x, fmaf(xv.y, wv.y, fmaf(xv.z, wv.z, fmaf(xv.w, wv.w, acc[k]))));
    }
  }
  int h = c >> 6, dh = c & 63;
  ushort_t* dst = qbuf + ((size_t)(b*4 + h) * 16) * 64 + dh;
  #pragma unroll
  for (int k = 0; k < 8; ++k) dst[k*64] = f2bf(acc[k] * 0.125f);  // SCALE folded in
  #pragma unroll
  for (int k = 8; k < 16; ++k) dst[k*64] = 0;                     // zero-pad rows 8..15
}

// ---------------- helpers: 4-row LN + 4-slot q projection (used by k_u2) ----------------
__device__ __forceinline__ void row_ln_4x(float (*S)[256], float (*L)[256],
                                          const float* __restrict__ w, const float* __restrict__ b, int t) {
  int k = t >> 6, ln = t & 63;     // one wave per row
  float s = 0.f, q = 0.f;
  #pragma unroll
  for (int j = 0; j < 4; ++j) { float v = S[k][ln + j*64]; s += v; q += v*v; }
  #pragma unroll
  for (int off = 32; off >= 1; off >>= 1) { s += __shfl_xor(s, off); q += __shfl_xor(q, off); }
  float m = s * (1.f/256.f);
  float rstd = rsqrtf(q * (1.f/256.f) - m*m + 1e-5f);
  #pragma unroll
  for (int j = 0; j < 4; ++j) {
    int c = ln + j*64;
    L[k][c] = (S[k][c] - m) * rstd * w[c] + b[c];
  }
}

__device__ __forceinline__ void qproj4(float (*L)[256], const float* __restrict__ Wq,
                                       ushort_t* __restrict__ qbuf, int b, int ks0, int t) {
  int c = t;
  const float4* Wrow = (const float4*)(Wq + (size_t)c * 256);
  float acc[4];
  #pragma unroll
  for (int k = 0; k < 4; ++k) acc[k] = 0.f;
  for (int i = 0; i < 64; ++i) {
    float4 wv = Wrow[i];
    #pragma unroll
    for (int k = 0; k < 4; ++k) {
      float4 xv = *((const float4*)&L[k][0] + i);
      acc[k] = fmaf(xv.x, wv.x, fmaf(xv.y, wv.y, fmaf(xv.z, wv.z, fmaf(xv.w, wv.w, acc[k]))));
    }
  }
  int h = c >> 6, dh = c & 63;
  ushort_t* dst = qbuf + ((size_t)(b*4 + h) * 16) * 64 + dh;
  #pragma unroll
  for (int k = 0; k < 4; ++k) dst[(ks0 + k)*64] = f2bf(acc[k] * 0.125f);
  #pragma unroll
  for (int k = 0; k < 4; ++k) dst[(8 + ks0 + k)*64] = 0;   // each half zeroes 4 pad rows
}

// ---------------- init: slots = mu + exp(log_sigma)*noise; q0 ----------------
__global__ __launch_bounds__(256) void k_init(const float* __restrict__ noise, const float* __restrict__ mu,
                                              const float* __restrict__ lsig, float* __restrict__ slots,
                                              const float* __restrict__ nsw, const float* __restrict__ nsb,
                                              const float* __restrict__ Wq, ushort_t* __restrict__ qbuf) {
  int b = blockIdx.x, t = threadIdx.x;
  __shared__ float S[8][256];
  __shared__ float L[8][256];
  float e = __expf(lsig[t]);
  float m = mu[t];
  #pragma unroll
  for (int k = 0; k < 8; ++k) {
    float v = m + e * noise[((size_t)(b*8+k))*256 + t];
    S[k][t] = v;
    slots[((size_t)(b*8+k))*256 + t] = v;
  }
  __syncthreads();
  row_ln_256(S, L, nsw, nsb, t);
  __syncthreads();
  qproj(L, Wq, qbuf, b, t);
}

// ---------------- big GEMM (stats fused): x[131072,256] x wkv[512,256]^T -> kf/vfT bf16 ----------------
// B staged via global_load_lds (pre-swizzled source); A reg-staged (f32->bf16 + stats).
__global__ __launch_bounds__(256, 3) void k_gemm(const float* __restrict__ x,
                                                 const ushort_t* __restrict__ wkv,
                                                 const float* __restrict__ c1, const float* __restrict__ c2,
                                                 ushort_t* __restrict__ kf, ushort_t* __restrict__ vfT) {
  // chunked remap: 16 chunks x (4 cb x 64 mb); same x-panel's 4 cb-blocks are 64 apart -> same XCD slot
  int wg = blockIdx.x;
  int chunk = wg >> 8;
  int within = wg & 255;
  int cb = within >> 6;
  int mb = (chunk << 6) | (within & 63);
  int t = threadIdx.x, w = t >> 6, l = t & 63;
  __shared__ uint4 ldsv[2048];               // 32 KiB: A dbuf @0/8192, B dbuf @16384/24576
  char* lds = (char*)ldsv;
  const int m0 = mb * 128, col0 = cb * 128;
  int r0 = t >> 1, half = t & 1;

  float4 xa[4];
  float ssum = 0.f, sqsum = 0.f;
  int swzW = ((r0 >> 1) & 3) << 4;

  auto loadA = [&](int s) {
    const float4* src = (const float4*)(x + (size_t)(m0 + r0) * 256 + s*32 + half*16);
    #pragma unroll
    for (int i = 0; i < 4; ++i) xa[i] = src[i];
  };
  auto writeA = [&](char* Ab) {
    #pragma unroll
    for (int i = 0; i < 2; ++i) {
      float4 a = xa[2*i], b2 = xa[2*i+1];
      ssum  += a.x + a.y + a.z + a.w + b2.x + b2.y + b2.z + b2.w;
      sqsum += a.x*a.x + a.y*a.y + a.z*a.z + a.w*a.w
             + b2.x*b2.x + b2.y*b2.y + b2.z*b2.z + b2.w*b2.w;
      union { ushort_t us[8]; uint4 v; } u;
      u.us[0]=f2bf(a.x);  u.us[1]=f2bf(a.y);  u.us[2]=f2bf(a.z);  u.us[3]=f2bf(a.w);
      u.us[4]=f2bf(b2.x); u.us[5]=f2bf(b2.y); u.us[6]=f2bf(b2.z); u.us[7]=f2bf(b2.w);
      *(uint4*)(Ab + r0*64 + ((half*32 + i*16) ^ swzW)) = u.v;
    }
  };
  // B via global_load_lds: linear LDS dest, pre-swizzled per-lane global source.
  // dest o = (w*2+j)*1024 + lane*16 -> row = (w*2+j)*16 + (l>>2); stored byte p=(l&3)*16
  // stored[p] must hold true col-byte p ^ swz(row) -> src elem += 8*((l&3) ^ ((row>>1)&3))
  int rB0 = (l >> 2);
  int permB = ((l & 3) ^ ((rB0 >> 1) & 3)) * 8;   // (row>>1)&3 depends only on l>>2 within 16-row group (rows 16-aligned)
  auto stageB = [&](int buf, int s) {
    char* Bb = lds + 16384 + (buf << 13);
    #pragma unroll
    for (int j = 0; j < 2; ++j) {
      int row = (w*2 + j)*16 + rB0;
      const ushort_t* src = wkv + (size_t)(col0 + row)*256 + s*32 + permB;
      gload_lds16(src, Bb + (w*2 + j)*1024);
    }
  };

  ffrag acc[4][4];
  #pragma unroll
  for (int i = 0; i < 4; ++i)
    #pragma unroll
    for (int j = 0; j < 4; ++j) acc[i][j] = (ffrag){0.f,0.f,0.f,0.f};

  int wm = w & 1, wn = w >> 1;
  int lrow = l & 15, lkb = ((l >> 4) * 8) * 2;   // frag col byte: 0/16/32/48

  loadA(0); writeA(lds);
  stageB(0, 0);
  __syncthreads();

  for (int s = 0; s < 8; ++s) {
    char* Ac = lds + ((s & 1) << 13);
    char* Bc = lds + 16384 + ((s & 1) << 13);
    if (s < 7) { loadA(s+1); stageB((s+1) & 1, s+1); }
    bfrag bfr[4];
    #pragma unroll
    for (int j = 0; j < 4; ++j) {
      int row = wn*64 + j*16 + lrow;
      bfr[j] = *(const bfrag*)(Bc + row*64 + (lkb ^ (((row >> 1) & 3) << 4)));
    }
    #pragma unroll
    for (int i = 0; i < 4; ++i) {
      int row = wm*64 + i*16 + lrow;
      bfrag afr = *(const bfrag*)(Ac + row*64 + (lkb ^ (((row >> 1) & 3) << 4)));
      #pragma unroll
      for (int j = 0; j < 4; ++j)
        acc[i][j] = __builtin_amdgcn_mfma_f32_16x16x32_bf16(afr, bfr[j], acc[i][j], 0, 0, 0);
    }
    if (s < 7) {
      char* An = lds + (((s+1) & 1) << 13);
      writeA(An);                      // safe: targets buffer read 2 steps ago
    }
    __syncthreads();
  }

  // ---- stats finalize (partner thread holds the other 128 cols of the row) ----
  float s2 = ssum  + __shfl_xor(ssum, 1);
  float q2 = sqsum + __shfl_xor(sqsum, 1);
  float* statm = (float*)(lds + 28672);
  float* statr = (float*)(lds + 29184);
  if (half == 0) {
    float mm = s2 * (1.f/256.f);
    statm[r0] = mm;
    statr[r0] = rsqrtf(q2 * (1.f/256.f) - mm*mm + 1e-5f);
  }
  __syncthreads();

  // ---- epilogue: val = rstd*(acc - mean*c1[n]) + c2[n], two 64-row/col passes through Ct @lds[0,17408) ----
  int g = l >> 4, nl = l & 15;
  int b = m0 >> 12, nx0 = m0 & 4095;
  if (cb < 2) {
    // kf path: Ct[m_local][col], pitch 136 halves
    for (int p = 0; p < 2; ++p) {
      if (wm == p) {
        #pragma unroll
        for (int i = 0; i < 4; ++i) {
          #pragma unroll
          for (int j = 0; j < 4; ++j) {
            int coll = wn*64 + j*16 + nl;
            float cc1 = c1[col0 + coll], cc2 = c2[col0 + coll];
            #pragma unroll
            for (int r = 0; r < 4; ++r) {
              int ml = i*16 + g*4 + r;           // local row in pass
              int mlg = p*64 + ml;
              float val = statr[mlg] * (acc[i][j][r] - statm[mlg] * cc1) + cc2;
              *(ushort_t*)(lds + (ml*136 + coll)*2) = f2bf(val);
            }
          }
        }
      }
      __syncthreads();
      {
        int mloc = t >> 2, hh = (t >> 1) & 1, qq = t & 1;
        int h = cb*2 + hh;
        ushort_t* dst = kf + ((size_t)((b*4 + h)*4096 + nx0 + p*64 + mloc)) * 64 + qq*32;
        const char* srcr = lds + mloc*272 + hh*128 + qq*64;
        #pragma unroll
        for (int jj = 0; jj < 4; ++jj)
          ((uint4*)dst)[jj] = *(const uint4*)(srcr + jj*16);
      }
      __syncthreads();
    }
  } else {
    // vf path (transposed): Ct[col_local][m], pitch 136 m-pairs (272 B)
    for (int p = 0; p < 2; ++p) {
      if (wn == p) {
        #pragma unroll
        for (int i = 0; i < 4; ++i) {
          int mlb = wm*64 + i*16 + g*4;
          #pragma unroll
          for (int j = 0; j < 4; ++j) {
            int coll = j*16 + nl;                // local col in pass
            int collg = p*64 + coll;
            float cc1 = c1[col0 + collg], cc2 = c2[col0 + collg];
            ushort_t us[4];
            #pragma unroll
            for (int r = 0; r < 4; ++r)
              us[r] = f2bf(statr[mlb+r] * (acc[i][j][r] - statm[mlb+r] * cc1) + cc2);
            *(uint2*)(lds + coll*272 + mlb*2) =
              make_uint2((unsigned)us[0] | ((unsigned)us[1] << 16),
                         (unsigned)us[2] | ((unsigned)us[3] << 16));
          }
        }
      }
      __syncthreads();
      {
        int cl = t >> 2, seg = t & 3;
        int collg = p*64 + cl;
        int h = (cb - 2)*2 + (collg >> 6);
        int dh = collg & 63;
        ushort_t* dst = vfT + ((size_t)((b*4 + h)*64 + dh)) * 4096 + nx0 + seg*32;
        const char* srcr = lds + cl*272 + seg*64;
        #pragma unroll
        for (int jj = 0; jj < 4; ++jj)
          ((uint4*)dst)[jj] = *(const uint4*)(srcr + jj*16);
      }
      __syncthreads();
    }
  }
}

// ---------------- attention: per (bh, 256-key chunk); K/V read direct from L2/L3 ----------------
__global__ __launch_bounds__(256, 4) void k_attn(const ushort_t* __restrict__ q, const ushort_t* __restrict__ kf,
                                                 const ushort_t* __restrict__ vfT,
                                                 float* __restrict__ updp, float* __restrict__ asump) {
  int split = blockIdx.x;   // 0..15
  int bh = blockIdx.y;      // 0..127
  int n0 = split * 256;
  int t = threadIdx.x, w = t >> 6, l = t & 63;
  __shared__ uint4 ldsv[640];            // 10240 B
  char* lds = (char*)ldsv;
  char* Pl = lds;                        // [16][512B] swizzled
  char* Ql = lds + 8192;                 // [16][128B] swizzled

  if (t < 128) { // stage Q (16x64, rows 8..15 pre-zeroed in qbuf)
    int k = t >> 3, seg = t & 7;
    uint4 v = *(const uint4*)(q + ((size_t)bh*16 + k) * 64 + seg*8);
    *(uint4*)(Ql + k*128 + ((seg*16) ^ ((k & 7) << 4))) = v;
  }
  // zero P rows 8..15 (A-operand padding)
  *(uint4*)(Pl + 4096 + t*16) = make_uint4(0,0,0,0);
  __syncthreads();

  int g = l >> 4, nl = l & 15, lk = g * 8;
  const ushort_t* kbase = kf + ((size_t)bh*4096 + n0) * 64;

  // dots = Q*K^T : each wave does 4 n-tiles of 16; K frags direct from global
  ffrag dacc[4];
  #pragma unroll
  for (int nt = 0; nt < 4; ++nt) {
    dacc[nt] = (ffrag){0.f,0.f,0.f,0.f};
    int row = w*64 + nt*16 + nl;
    #pragma unroll
    for (int kk = 0; kk < 2; ++kk) {
      bfrag af = *(const bfrag*)(Ql + nl*128 + (((kk*32 + lk)*2) ^ ((nl & 7) << 4)));
      bfrag bf = *(const bfrag*)(kbase + (size_t)row*64 + kk*32 + lk);
      dacc[nt] = __builtin_amdgcn_mfma_f32_16x16x32_bf16(af, bf, dacc[nt], 0, 0, 0);
    }
  }

  // softmax over k (8 slots) per column n; accumulate asum; write P (bf16) to LDS
  float asr0 = 0.f, asr1 = 0.f, asr2 = 0.f, asr3 = 0.f;
  #pragma unroll
  for (int nt = 0; nt < 4; ++nt) {
    float d0 = dacc[nt][0], d1 = dacc[nt][1], d2 = dacc[nt][2], d3 = dacc[nt][3];
    float mx = fmaxf(fmaxf(d0, d1), fmaxf(d2, d3));
    mx = fmaxf(mx, __shfl_xor(mx, 16));
    float p0 = __expf(d0 - mx), p1 = __expf(d1 - mx), p2 = __expf(d2 - mx), p3 = __expf(d3 - mx);
    float sden = p0 + p1 + p2 + p3;
    sden += __shfl_xor(sden, 16);
    float inv = 1.f / sden;
    p0 *= inv; p1 *= inv; p2 *= inv; p3 *= inv;
    if (g < 2) {
      asr0 += p0; asr1 += p1; asr2 += p2; asr3 += p3;
      int n = w*64 + nt*16 + nl;
      int k0 = g*4;
      *(ushort_t*)(Pl + (((k0+0)*512 + n*2) ^ (((k0+0)&7) << 4))) = f2bf(p0);
      *(ushort_t*)(Pl + (((k0+1)*512 + n*2) ^ (((k0+1)&7) << 4))) = f2bf(p1);
      *(ushort_t*)(Pl + (((k0+2)*512 + n*2) ^ (((k0+2)&7) << 4))) = f2bf(p2);
      *(ushort_t*)(Pl + (((k0+3)*512 + n*2) ^ (((k0+3)&7) << 4))) = f2bf(p3);
    }
  }
  #pragma unroll
  for (int off = 8; off >= 1; off >>= 1) {
    asr0 += __shfl_xor(asr0, off); asr1 += __shfl_xor(asr1, off);
    asr2 += __shfl_xor(asr2, off); asr3 += __shfl_xor(asr3, off);
  }
  if (g < 2 && nl == 0) {
    float* dst = asump + (((size_t)bh*16 + split)*4 + w)*8 + g*4;
    dst[0] = asr0; dst[1] = asr1; dst[2] = asr2; dst[3] = asr3;
  }
  __syncthreads();

  // upd_partial = P @ V : wave w owns d-tile [w*16, w*16+16); V frags direct from global
  const ushort_t* vbase = vfT + ((size_t)bh*64) * 4096 + n0;
  ffrag pacc = (ffrag){0.f,0.f,0.f,0.f};
  int d = w*16 + nl;
  #pragma unroll
  for (int ni = 0; ni < 8; ++ni) {
    int nn = ni * 32;
    bfrag af = *(const bfrag*)(Pl + nl*512 + (((nn + lk)*2) ^ ((nl & 7) << 4)));
    bfrag bf = *(const bfrag*)(vbase + (size_t)d*4096 + nn + lk);
    pacc = __builtin_amdgcn_mfma_f32_16x16x32_bf16(af, bf, pacc, 0, 0, 0);
  }
  if (g < 2) {
    float* dst = updp + (((size_t)bh*16 + split)*8 + g*4)*64 + w*16 + nl;
    #pragma unroll
    for (int r = 0; r < 4; ++r) dst[r*64] = pacc[r];
  }
}

// ---------------- U1 (fin fused): gi = (sum updp / (sum asum + eps)) @ Wf^T + bih ; gh = slots@Whh^T + bhh ----------------
__global__ __launch_bounds__(256) void k_u1(const float* __restrict__ updp, const float* __restrict__ asump,
                                            const float* __restrict__ slots,
                                            const float* __restrict__ Wf, const float* __restrict__ Whh,
                                            const float* __restrict__ bih, const float* __restrict__ bhh,
                                            float* __restrict__ gi, float* __restrict__ gh) {
  int cb = blockIdx.x, b = blockIdx.y, t = threadIdx.x;
  int c = cb * 256 + t;                 // 0..1535
  bool isGi = (c < 768);                // block-uniform (cb<3)
  __shared__ float X[8][256];
  __shared__ float asumS[4][8];
  if (isGi) {
    if (t < 32) {
      int h = t >> 3, kk = t & 7;
      const float* ap = asump + (size_t)(b*4 + h) * 512;
      float a = 0.f;
      #pragma unroll
      for (int s = 0; s < 64; ++s) a += ap[s*8 + kk];
      asumS[h][kk] = a + 1e-8f;
    }
    __syncthreads();
    int h = t >> 6, d = t & 63;
    const float* up = updp + (size_t)(b*4 + h) * 8192 + d;
    #pragma unroll
    for (int k = 0; k < 8; ++k) {
      float u = 0.f;
      #pragma unroll
      for (int s = 0; s < 16; ++s) u += up[s*512 + k*64];
      X[k][t] = u / asumS[h][k];
    }
  } else {
    #pragma unroll
    for (int k = 0; k < 8; ++k) X[k][t] = slots[((size_t)(b*8+k))*256 + t];
  }
  __syncthreads();
  int cc = isGi ? c : (c - 768);
  const float* Wrow = (isGi ? Wf : Whh) + (size_t)cc * 256;
  float bias = isGi ? bih[cc] : bhh[cc];
  float acc[8];
  #pragma unroll
  for (int k = 0; k < 8; ++k) acc[k] = bias;
  for (int i = 0; i < 64; ++i) {
    float4 wv = ((const float4*)Wrow)[i];
    #pragma unroll
    for (int k = 0; k < 8; ++k) {
      float4 xv = *((const float4*)&X[k][0] + i);
      acc[k] = fmaf(xv.x, wv.x, fmaf(xv.y, wv.y, fmaf(xv.z, wv.z, fmaf(xv.w, wv.w, acc[k]))));
    }
  }
  float* dst = isGi ? gi : gh;
  #pragma unroll
  for (int k = 0; k < 8; ++k) dst[((size_t)(b*8+k))*768 + cc] = acc[k];
}

// ---------------- U2: GRU + LN + MLP (+ next-iter q), 4 slots per block ----------------
__global__ __launch_bounds__(256) void k_u2(const float* __restrict__ gi, const float* __restrict__ gh,
                                            const float* __restrict__ slots_in, float* __restrict__ slots_out,
                                            const float* __restrict__ nmw, const float* __restrict__ nmb,
                                            const float* __restrict__ W1, const float* __restrict__ b1,
                                            const float* __restrict__ W2, const float* __restrict__ b2,
                                            const float* __restrict__ nsw, const float* __restrict__ nsb,
                                            const float* __restrict__ Wq, ushort_t* __restrict__ qbuf, int do_q) {
  int bid = blockIdx.x;
  int b = bid >> 1, ks0 = (bid & 1) * 4;
  int t = threadIdx.x;
  __shared__ float S[4][256];
  __shared__ float L[4][256];
  __shared__ float H1[4][256];
  // GRU
  #pragma unroll
  for (int k = 0; k < 4; ++k) {
    int slot = b*8 + ks0 + k;
    size_t gb = (size_t)slot * 768;
    float ir = gi[gb + t],        hr = gh[gb + t];
    float iz = gi[gb + 256 + t],  hz = gh[gb + 256 + t];
    float in_ = gi[gb + 512 + t], hn = gh[gb + 512 + t];
    float r = 1.f / (1.f + __expf(-(ir + hr)));
    float z = 1.f / (1.f + __expf(-(iz + hz)));
    float a = in_ + r * hn;
    float e2 = __expf(-2.f * fabsf(a));
    float nn = (1.f - e2) / (1.f + e2);
    nn = copysignf(nn, a);
    S[k][t] = (1.f - z) * nn + z * slots_in[(size_t)slot * 256 + t];
  }
  __syncthreads();
  row_ln_4x(S, L, nmw, nmb, t);
  __syncthreads();
  { // h1 = relu(L @ W1^T + b1)
    const float4* Wrow = (const float4*)(W1 + (size_t)t * 256);
    float bb = b1[t];
    float acc[4];
    #pragma unroll
    for (int k = 0; k < 4; ++k) acc[k] = bb;
    for (int i = 0; i < 64; ++i) {
      float4 wv = Wrow[i];
      #pragma unroll
      for (int k = 0; k < 4; ++k) {
        float4 xv = *((const float4*)&L[k][0] + i);
        acc[k] = fmaf(xv.x, wv.x, fmaf(xv.y, wv.y, fmaf(xv.z, wv.z, fmaf(xv.w, wv.w, acc[k]))));
      }
    }
    #pragma unroll
    for (int k = 0; k < 4; ++k) H1[k][t] = fmaxf(acc[k], 0.f);
  }
  __syncthreads();
  { // out = S + H1 @ W2^T + b2
    const float4* Wrow = (const float4*)(W2 + (size_t)t * 256);
    float bb = b2[t];
    float acc[4];
    #pragma unroll
    for (int k = 0; k < 4; ++k) acc[k] = bb;
    for (int i = 0; i < 64; ++i) {
      float4 wv = Wrow[i];
      #pragma unroll
      for (int k = 0; k < 4; ++k) {
        float4 xv = *((const float4*)&H1[k][0] + i);
        acc[k] = fmaf(xv.x, wv.x, fmaf(xv.y, wv.y, fmaf(xv.z, wv.z, fmaf(xv.w, wv.w, acc[k]))));
      }
    }
    #pragma unroll
    for (int k = 0; k < 4; ++k) {
      int slot = b*8 + ks0 + k;
      float o = S[k][t] + acc[k];
      slots_out[(size_t)slot * 256 + t] = o;
      S[k][t] = o;
    }
  }
  __syncthreads();
  if (do_q) {
    row_ln_4x(S, L, nsw, nsb, t);
    __syncthreads();
    qproj4(L, Wq, qbuf, b, ks0, t);
  }
}

// ---------------- launch ----------------
extern "C" void kernel_launch(void* const* d_in, const int* in_sizes, int n_in,
                              void* d_out, int out_size, void* d_ws, size_t ws_size,
                              hipStream_t stream) {
  (void)in_sizes; (void)n_in; (void)out_size; (void)ws_size;
  const float* x     = (const float*)d_in[0];
  const float* noise = (const float*)d_in[1];
  const float* mu    = (const float*)d_in[2];
  const float* lsig  = (const float*)d_in[3];
  const float* ninw  = (const float*)d_in[4];
  const float* ninb  = (const float*)d_in[5];
  const float* nsw   = (const float*)d_in[6];
  const float* nsb   = (const float*)d_in[7];
  const float* nmw   = (const float*)d_in[8];
  const float* nmb   = (const float*)d_in[9];
  const float* Wq    = (const float*)d_in[10];
  const float* Wk    = (const float*)d_in[11];
  const float* Wv    = (const float*)d_in[12];
  const float* Wo    = (const float*)d_in[13];
  const float* Wih   = (const float*)d_in[14];
  const float* Whh   = (const float*)d_in[15];
  const float* bih   = (const float*)d_in[16];
  const float* bhh   = (const float*)d_in[17];
  const float* W1    = (const float*)d_in[18];
  const float* b1    = (const float*)d_in[19];
  const float* W2    = (const float*)d_in[20];
  const float* b2    = (const float*)d_in[21];

  char* ws = (char*)d_ws;
  ushort_t* wkv   = (ushort_t*)(ws + 0);          //   262,144
  float*    c1    = (float*)   (ws + 262144);     //     2,048
  float*    c2    = (float*)   (ws + 264192);     //     2,048
  float*    Wf    = (float*)   (ws + 266240);     //   786,432
  float*    slots = (float*)   (ws + 1052672);    //   262,144
  ushort_t* qbuf  = (ushort_t*)(ws + 1314816);    //   262,144
  float*    gi    = (float*)   (ws + 1839104);    //   786,432
  float*    gh    = (float*)   (ws + 2625536);    //   786,432
  float*    asump = (float*)   (ws + 3411968);    //   262,144
  float*    updp  = (float*)   (ws + 3674112);    // 4,194,304
  ushort_t* kf    = (ushort_t*)(ws + 7868416);    // 67,108,864
  ushort_t* vfT   = (ushort_t*)(ws + 74977280);   // 67,108,864  (total 142,086,144)

  k_prep_wkv<<<512,  256, 0, stream>>>(Wk, Wv, ninw, ninb, wkv, c1, c2);
  k_gemm    <<<4096, 256, 0, stream>>>(x, wkv, c1, c2, kf, vfT);
  k_prep_wf <<<768,  256, 0, stream>>>(Wih, Wo, Wf);
  k_init    <<<32,   256, 0, stream>>>(noise, mu, lsig, slots, nsw, nsb, Wq, qbuf);

  float* outp = (float*)d_out;
  for (int it = 0; it < 3; ++it) {
    k_attn<<<dim3(16, 128), 256, 0, stream>>>(qbuf, kf, vfT, updp, asump);
    k_u1  <<<dim3(6, 32),   256, 0, stream>>>(updp, asump, slots, Wf, Whh, bih, bhh, gi, gh);
    k_u2  <<<64,            256, 0, stream>>>(gi, gh, slots, (it == 2) ? outp : slots,
                                              nmw, nmb, W1, b1, W2, b2, nsw, nsb, Wq, qbuf, (it < 2) ? 1 : 0);
  }
}

// Round 6
// 549.170 us; speedup vs baseline: 1.1094x; 1.1094x over previous
//
#include <hip/hip_runtime.h>
#include <stdint.h>

typedef unsigned short ushort_t;
typedef __attribute__((ext_vector_type(8))) short bfrag;   // 8 x bf16 (bit pattern)
typedef __attribute__((ext_vector_type(4))) float ffrag;   // mfma f32x4 acc

#define B_  32
#define K_  8
#define N_  4096
#define D_  256
#define H_  4
#define DH_ 64

__device__ __forceinline__ ushort_t f2bf(float f) {
  unsigned int u = __builtin_bit_cast(unsigned int, f);
  u += 0x7FFFu + ((u >> 16) & 1u);           // round-nearest-even
  return (ushort_t)(u >> 16);
}

__device__ __forceinline__ void gload_lds16(const void* g, void* l) {
  __builtin_amdgcn_global_load_lds((const __attribute__((address_space(1))) unsigned int*)g,
                                   (__attribute__((address_space(3))) unsigned int*)l,
                                   16, 0, 0);
}

// ---------------- prep: wkv' = ln_w * [Wk;Wv] (bf16), c1=rowsum(wkv'), c2=rowdot(ln_b, W) ----------------
__global__ __launch_bounds__(256) void k_prep_wkv(const float* __restrict__ Wk, const float* __restrict__ Wv,
                                                  const float* __restrict__ lnw, const float* __restrict__ lnb,
                                                  ushort_t* __restrict__ wkv,
                                                  float* __restrict__ c1, float* __restrict__ c2) {
  int n = blockIdx.x;           // 0..511
  int i = threadIdx.x;          // 0..255
  float wv = (n < 256) ? Wk[n*256 + i] : Wv[(n-256)*256 + i];
  float wp = lnw[i] * wv;
  wkv[n*256 + i] = f2bf(wp);
  float p1 = wp, p2 = lnb[i] * wv;
  #pragma unroll
  for (int off = 32; off >= 1; off >>= 1) { p1 += __shfl_xor(p1, off); p2 += __shfl_xor(p2, off); }
  __shared__ float r1[4], r2[4];
  int w = threadIdx.x >> 6;
  if ((threadIdx.x & 63) == 0) { r1[w] = p1; r2[w] = p2; }
  __syncthreads();
  if (threadIdx.x == 0) { c1[n] = r1[0]+r1[1]+r1[2]+r1[3]; c2[n] = r2[0]+r2[1]+r2[2]+r2[3]; }
}

// ---------------- prep: Wfused = Wih @ Wo  ([768,256]) ----------------
__global__ __launch_bounds__(256) void k_prep_wf(const float* __restrict__ Wih, const float* __restrict__ Wo,
                                                 float* __restrict__ Wf) {
  int j = blockIdx.x;   // 0..767
  int i = threadIdx.x;  // 0..255
  __shared__ float row[256];
  row[i] = Wih[j*256 + i];
  __syncthreads();
  float acc = 0.f;
  #pragma unroll 8
  for (int t = 0; t < 256; ++t) acc += row[t] * Wo[t*256 + i];
  Wf[j*256 + i] = acc;
}

// ---------------- helpers: 8-row LN + 8-slot q projection (used by k_init) ----------------
__device__ __forceinline__ void row_ln_256(float (*S)[256], float (*L)[256],
                                           const float* __restrict__ w, const float* __restrict__ b, int t) {
  int k = t >> 5, ln = t & 31;
  float s = 0.f, q = 0.f;
  #pragma unroll
  for (int j = 0; j < 8; ++j) { float v = S[k][ln + j*32]; s += v; q += v*v; }
  #pragma unroll
  for (int off = 16; off >= 1; off >>= 1) { s += __shfl_xor(s, off); q += __shfl_xor(q, off); }
  float m = s * (1.f/256.f);
  float rstd = rsqrtf(q * (1.f/256.f) - m*m + 1e-5f);
  #pragma unroll
  for (int j = 0; j < 8; ++j) {
    int c = ln + j*32;
    L[k][c] = (S[k][c] - m) * rstd * w[c] + b[c];
  }
}

__device__ __forceinline__ void qproj(float (*L)[256], const float* __restrict__ Wq,
                                      ushort_t* __restrict__ qbuf, int b, int t) {
  int c = t;
  const float4* Wrow = (const float4*)(Wq + (size_t)c * 256);
  float acc[8];
  #pragma unroll
  for (int k = 0; k < 8; ++k) acc[k] = 0.f;
  for (int i = 0; i < 64; ++i) {
    float4 wv = Wrow[i];
    #pragma unroll
    for (int k = 0; k < 8; ++k) {
      float4 xv = *((const float4*)&L[k][0] + i);
      acc[k] = fmaf(xv.x, wv.x, fmaf(xv.y, wv.y, fmaf(xv.z, wv.z, fmaf(xv.w, wv.w, acc[k]))));
    }
  }
  int h = c >> 6, dh = c & 63;
  ushort_t* dst = qbuf + ((size_t)(b*4 + h) * 16) * 64 + dh;
  #pragma unroll
  for (int k = 0; k < 8; ++k) dst[k*64] = f2bf(acc[k] * 0.125f);  // SCALE folded in
  #pragma unroll
  for (int k = 8; k < 16; ++k) dst[k*64] = 0;                     // zero-pad rows 8..15
}

// ---------------- helpers: 4-row LN + 4-slot q projection (used by k_u2) ----------------
__device__ __forceinline__ void row_ln_4x(float (*S)[256], float (*L)[256],
                                          const float* __restrict__ w, const float* __restrict__ b, int t) {
  int k = t >> 6, ln = t & 63;     // one wave per row
  float s = 0.f, q = 0.f;
  #pragma unroll
  for (int j = 0; j < 4; ++j) { float v = S[k][ln + j*64]; s += v; q += v*v; }
  #pragma unroll
  for (int off = 32; off >= 1; off >>= 1) { s += __shfl_xor(s, off); q += __shfl_xor(q, off); }
  float m = s * (1.f/256.f);
  float rstd = rsqrtf(q * (1.f/256.f) - m*m + 1e-5f);
  #pragma unroll
  for (int j = 0; j < 4; ++j) {
    int c = ln + j*64;
    L[k][c] = (S[k][c] - m) * rstd * w[c] + b[c];
  }
}

__device__ __forceinline__ void qproj4(float (*L)[256], const float* __restrict__ Wq,
                                       ushort_t* __restrict__ qbuf, int b, int ks0, int t) {
  int c = t;
  const float4* Wrow = (const float4*)(Wq + (size_t)c * 256);
  float acc[4];
  #pragma unroll
  for (int k = 0; k < 4; ++k) acc[k] = 0.f;
  for (int i = 0; i < 64; ++i) {
    float4 wv = Wrow[i];
    #pragma unroll
    for (int k = 0; k < 4; ++k) {
      float4 xv = *((const float4*)&L[k][0] + i);
      acc[k] = fmaf(xv.x, wv.x, fmaf(xv.y, wv.y, fmaf(xv.z, wv.z, fmaf(xv.w, wv.w, acc[k]))));
    }
  }
  int h = c >> 6, dh = c & 63;
  ushort_t* dst = qbuf + ((size_t)(b*4 + h) * 16) * 64 + dh;
  #pragma unroll
  for (int k = 0; k < 4; ++k) dst[(ks0 + k)*64] = f2bf(acc[k] * 0.125f);
  #pragma unroll
  for (int k = 0; k < 4; ++k) dst[(8 + ks0 + k)*64] = 0;   // each half zeroes 4 pad rows
}

// ---------------- init: slots = mu + exp(log_sigma)*noise; q0 ----------------
__global__ __launch_bounds__(256) void k_init(const float* __restrict__ noise, const float* __restrict__ mu,
                                              const float* __restrict__ lsig, float* __restrict__ slots,
                                              const float* __restrict__ nsw, const float* __restrict__ nsb,
                                              const float* __restrict__ Wq, ushort_t* __restrict__ qbuf) {
  int b = blockIdx.x, t = threadIdx.x;
  __shared__ float S[8][256];
  __shared__ float L[8][256];
  float e = __expf(lsig[t]);
  float m = mu[t];
  #pragma unroll
  for (int k = 0; k < 8; ++k) {
    float v = m + e * noise[((size_t)(b*8+k))*256 + t];
    S[k][t] = v;
    slots[((size_t)(b*8+k))*256 + t] = v;
  }
  __syncthreads();
  row_ln_256(S, L, nsw, nsb, t);
  __syncthreads();
  qproj(L, Wq, qbuf, b, t);
}

// ---------------- big GEMM (stats fused): x[131072,256] x wkv[512,256]^T -> kf/vfT bf16 ----------------
// B staged via global_load_lds (pre-swizzled source); A reg-staged (f32->bf16 + stats).
// launch_bounds(256,2): allocator free up to 256 regs -> no spill; actual ~160 total still fits 3 waves/SIMD.
__global__ __launch_bounds__(256, 2) void k_gemm(const float* __restrict__ x,
                                                 const ushort_t* __restrict__ wkv,
                                                 const float* __restrict__ c1, const float* __restrict__ c2,
                                                 ushort_t* __restrict__ kf, ushort_t* __restrict__ vfT) {
  // chunked remap: 16 chunks x (4 cb x 64 mb); same x-panel's 4 cb-blocks are 64 apart -> same XCD slot
  int wg = blockIdx.x;
  int chunk = wg >> 8;
  int within = wg & 255;
  int cb = within >> 6;
  int mb = (chunk << 6) | (within & 63);
  int t = threadIdx.x, w = t >> 6, l = t & 63;
  __shared__ uint4 ldsv[2048];               // 32 KiB: A dbuf @0/8192, B dbuf @16384/24576
  char* lds = (char*)ldsv;
  const int m0 = mb * 128, col0 = cb * 128;
  int r0 = t >> 1, half = t & 1;

  float4 xa[4];
  float ssum = 0.f, sqsum = 0.f;
  int swzW = ((r0 >> 1) & 3) << 4;

  auto loadA = [&](int s) {
    const float4* src = (const float4*)(x + (size_t)(m0 + r0) * 256 + s*32 + half*16);
    #pragma unroll
    for (int i = 0; i < 4; ++i) xa[i] = src[i];
  };
  auto writeA = [&](char* Ab) {
    #pragma unroll
    for (int i = 0; i < 2; ++i) {
      float4 a = xa[2*i], b2 = xa[2*i+1];
      ssum  += a.x + a.y + a.z + a.w + b2.x + b2.y + b2.z + b2.w;
      sqsum += a.x*a.x + a.y*a.y + a.z*a.z + a.w*a.w
             + b2.x*b2.x + b2.y*b2.y + b2.z*b2.z + b2.w*b2.w;
      union { ushort_t us[8]; uint4 v; } u;
      u.us[0]=f2bf(a.x);  u.us[1]=f2bf(a.y);  u.us[2]=f2bf(a.z);  u.us[3]=f2bf(a.w);
      u.us[4]=f2bf(b2.x); u.us[5]=f2bf(b2.y); u.us[6]=f2bf(b2.z); u.us[7]=f2bf(b2.w);
      *(uint4*)(Ab + r0*64 + ((half*32 + i*16) ^ swzW)) = u.v;
    }
  };
  // B via global_load_lds: linear LDS dest, pre-swizzled per-lane global source.
  int rB0 = (l >> 2);
  int permB = ((l & 3) ^ ((rB0 >> 1) & 3)) * 8;
  auto stageB = [&](int buf, int s) {
    char* Bb = lds + 16384 + (buf << 13);
    #pragma unroll
    for (int j = 0; j < 2; ++j) {
      int row = (w*2 + j)*16 + rB0;
      const ushort_t* src = wkv + (size_t)(col0 + row)*256 + s*32 + permB;
      gload_lds16(src, Bb + (w*2 + j)*1024);
    }
  };

  ffrag acc[4][4];
  #pragma unroll
  for (int i = 0; i < 4; ++i)
    #pragma unroll
    for (int j = 0; j < 4; ++j) acc[i][j] = (ffrag){0.f,0.f,0.f,0.f};

  int wm = w & 1, wn = w >> 1;
  int lrow = l & 15, lkb = ((l >> 4) * 8) * 2;   // frag col byte: 0/16/32/48

  loadA(0); writeA(lds);
  stageB(0, 0);
  __syncthreads();

  for (int s = 0; s < 8; ++s) {
    char* Ac = lds + ((s & 1) << 13);
    char* Bc = lds + 16384 + ((s & 1) << 13);
    if (s < 7) { loadA(s+1); stageB((s+1) & 1, s+1); }
    bfrag bfr[4];
    #pragma unroll
    for (int j = 0; j < 4; ++j) {
      int row = wn*64 + j*16 + lrow;
      bfr[j] = *(const bfrag*)(Bc + row*64 + (lkb ^ (((row >> 1) & 3) << 4)));
    }
    #pragma unroll
    for (int i = 0; i < 4; ++i) {
      int row = wm*64 + i*16 + lrow;
      bfrag afr = *(const bfrag*)(Ac + row*64 + (lkb ^ (((row >> 1) & 3) << 4)));
      #pragma unroll
      for (int j = 0; j < 4; ++j)
        acc[i][j] = __builtin_amdgcn_mfma_f32_16x16x32_bf16(afr, bfr[j], acc[i][j], 0, 0, 0);
    }
    if (s < 7) {
      char* An = lds + (((s+1) & 1) << 13);
      writeA(An);                      // safe: targets buffer read 2 steps ago
    }
    __syncthreads();
  }

  // ---- stats finalize (partner thread holds the other 128 cols of the row) ----
  float s2 = ssum  + __shfl_xor(ssum, 1);
  float q2 = sqsum + __shfl_xor(sqsum, 1);
  float* statm = (float*)(lds + 28672);
  float* statr = (float*)(lds + 29184);
  if (half == 0) {
    float mm = s2 * (1.f/256.f);
    statm[r0] = mm;
    statr[r0] = rsqrtf(q2 * (1.f/256.f) - mm*mm + 1e-5f);
  }
  __syncthreads();

  // ---- epilogue: val = rstd*(acc - mean*c1[n]) + c2[n], two 64-row/col passes through Ct @lds[0,17408) ----
  int g = l >> 4, nl = l & 15;
  int b = m0 >> 12, nx0 = m0 & 4095;
  if (cb < 2) {
    // kf path: Ct[m_local][col], pitch 136 halves
    for (int p = 0; p < 2; ++p) {
      if (wm == p) {
        #pragma unroll
        for (int i = 0; i < 4; ++i) {
          #pragma unroll
          for (int j = 0; j < 4; ++j) {
            int coll = wn*64 + j*16 + nl;
            float cc1 = c1[col0 + coll], cc2 = c2[col0 + coll];
            #pragma unroll
            for (int r = 0; r < 4; ++r) {
              int ml = i*16 + g*4 + r;           // local row in pass
              int mlg = p*64 + ml;
              float val = statr[mlg] * (acc[i][j][r] - statm[mlg] * cc1) + cc2;
              *(ushort_t*)(lds + (ml*136 + coll)*2) = f2bf(val);
            }
          }
        }
      }
      __syncthreads();
      {
        int mloc = t >> 2, hh = (t >> 1) & 1, qq = t & 1;
        int h = cb*2 + hh;
        ushort_t* dst = kf + ((size_t)((b*4 + h)*4096 + nx0 + p*64 + mloc)) * 64 + qq*32;
        const char* srcr = lds + mloc*272 + hh*128 + qq*64;
        #pragma unroll
        for (int jj = 0; jj < 4; ++jj)
          ((uint4*)dst)[jj] = *(const uint4*)(srcr + jj*16);
      }
      __syncthreads();
    }
  } else {
    // vf path (transposed): Ct[col_local][m], pitch 136 m-pairs (272 B)
    for (int p = 0; p < 2; ++p) {
      if (wn == p) {
        #pragma unroll
        for (int i = 0; i < 4; ++i) {
          int mlb = wm*64 + i*16 + g*4;
          #pragma unroll
          for (int j = 0; j < 4; ++j) {
            int coll = j*16 + nl;                // local col in pass
            int collg = p*64 + coll;
            float cc1 = c1[col0 + collg], cc2 = c2[col0 + collg];
            ushort_t us[4];
            #pragma unroll
            for (int r = 0; r < 4; ++r)
              us[r] = f2bf(statr[mlb+r] * (acc[i][j][r] - statm[mlb+r] * cc1) + cc2);
            *(uint2*)(lds + coll*272 + mlb*2) =
              make_uint2((unsigned)us[0] | ((unsigned)us[1] << 16),
                         (unsigned)us[2] | ((unsigned)us[3] << 16));
          }
        }
      }
      __syncthreads();
      {
        int cl = t >> 2, seg = t & 3;
        int collg = p*64 + cl;
        int h = (cb - 2)*2 + (collg >> 6);
        int dh = collg & 63;
        ushort_t* dst = vfT + ((size_t)((b*4 + h)*64 + dh)) * 4096 + nx0 + seg*32;
        const char* srcr = lds + cl*272 + seg*64;
        #pragma unroll
        for (int jj = 0; jj < 4; ++jj)
          ((uint4*)dst)[jj] = *(const uint4*)(srcr + jj*16);
      }
      __syncthreads();
    }
  }
}

// ---------------- attention: per (bh, 256-key chunk); K/V read direct from L2/L3 ----------------
__global__ __launch_bounds__(256, 4) void k_attn(const ushort_t* __restrict__ q, const ushort_t* __restrict__ kf,
                                                 const ushort_t* __restrict__ vfT,
                                                 float* __restrict__ updp, float* __restrict__ asump) {
  int split = blockIdx.x;   // 0..15
  int bh = blockIdx.y;      // 0..127
  int n0 = split * 256;
  int t = threadIdx.x, w = t >> 6, l = t & 63;
  __shared__ uint4 ldsv[640];            // 10240 B
  char* lds = (char*)ldsv;
  char* Pl = lds;                        // [16][512B] swizzled
  char* Ql = lds + 8192;                 // [16][128B] swizzled

  if (t < 128) { // stage Q (16x64, rows 8..15 pre-zeroed in qbuf)
    int k = t >> 3, seg = t & 7;
    uint4 v = *(const uint4*)(q + ((size_t)bh*16 + k) * 64 + seg*8);
    *(uint4*)(Ql + k*128 + ((seg*16) ^ ((k & 7) << 4))) = v;
  }
  // zero P rows 8..15 (A-operand padding)
  *(uint4*)(Pl + 4096 + t*16) = make_uint4(0,0,0,0);
  __syncthreads();

  int g = l >> 4, nl = l & 15, lk = g * 8;
  const ushort_t* kbase = kf + ((size_t)bh*4096 + n0) * 64;

  // dots = Q*K^T : each wave does 4 n-tiles of 16; K frags direct from global
  ffrag dacc[4];
  #pragma unroll
  for (int nt = 0; nt < 4; ++nt) {
    dacc[nt] = (ffrag){0.f,0.f,0.f,0.f};
    int row = w*64 + nt*16 + nl;
    #pragma unroll
    for (int kk = 0; kk < 2; ++kk) {
      bfrag af = *(const bfrag*)(Ql + nl*128 + (((kk*32 + lk)*2) ^ ((nl & 7) << 4)));
      bfrag bf = *(const bfrag*)(kbase + (size_t)row*64 + kk*32 + lk);
      dacc[nt] = __builtin_amdgcn_mfma_f32_16x16x32_bf16(af, bf, dacc[nt], 0, 0, 0);
    }
  }

  // softmax over k (8 slots) per column n; accumulate asum; write P (bf16) to LDS
  float asr0 = 0.f, asr1 = 0.f, asr2 = 0.f, asr3 = 0.f;
  #pragma unroll
  for (int nt = 0; nt < 4; ++nt) {
    float d0 = dacc[nt][0], d1 = dacc[nt][1], d2 = dacc[nt][2], d3 = dacc[nt][3];
    float mx = fmaxf(fmaxf(d0, d1), fmaxf(d2, d3));
    mx = fmaxf(mx, __shfl_xor(mx, 16));
    float p0 = __expf(d0 - mx), p1 = __expf(d1 - mx), p2 = __expf(d2 - mx), p3 = __expf(d3 - mx);
    float sden = p0 + p1 + p2 + p3;
    sden += __shfl_xor(sden, 16);
    float inv = 1.f / sden;
    p0 *= inv; p1 *= inv; p2 *= inv; p3 *= inv;
    if (g < 2) {
      asr0 += p0; asr1 += p1; asr2 += p2; asr3 += p3;
      int n = w*64 + nt*16 + nl;
      int k0 = g*4;
      *(ushort_t*)(Pl + (((k0+0)*512 + n*2) ^ (((k0+0)&7) << 4))) = f2bf(p0);
      *(ushort_t*)(Pl + (((k0+1)*512 + n*2) ^ (((k0+1)&7) << 4))) = f2bf(p1);
      *(ushort_t*)(Pl + (((k0+2)*512 + n*2) ^ (((k0+2)&7) << 4))) = f2bf(p2);
      *(ushort_t*)(Pl + (((k0+3)*512 + n*2) ^ (((k0+3)&7) << 4))) = f2bf(p3);
    }
  }
  #pragma unroll
  for (int off = 8; off >= 1; off >>= 1) {
    asr0 += __shfl_xor(asr0, off); asr1 += __shfl_xor(asr1, off);
    asr2 += __shfl_xor(asr2, off); asr3 += __shfl_xor(asr3, off);
  }
  if (g < 2 && nl == 0) {
    float* dst = asump + (((size_t)bh*16 + split)*4 + w)*8 + g*4;
    dst[0] = asr0; dst[1] = asr1; dst[2] = asr2; dst[3] = asr3;
  }
  __syncthreads();

  // upd_partial = P @ V : wave w owns d-tile [w*16, w*16+16); V frags direct from global
  const ushort_t* vbase = vfT + ((size_t)bh*64) * 4096 + n0;
  ffrag pacc = (ffrag){0.f,0.f,0.f,0.f};
  int d = w*16 + nl;
  #pragma unroll
  for (int ni = 0; ni < 8; ++ni) {
    int nn = ni * 32;
    bfrag af = *(const bfrag*)(Pl + nl*512 + (((nn + lk)*2) ^ ((nl & 7) << 4)));
    bfrag bf = *(const bfrag*)(vbase + (size_t)d*4096 + nn + lk);
    pacc = __builtin_amdgcn_mfma_f32_16x16x32_bf16(af, bf, pacc, 0, 0, 0);
  }
  if (g < 2) {
    float* dst = updp + (((size_t)bh*16 + split)*8 + g*4)*64 + w*16 + nl;
    #pragma unroll
    for (int r = 0; r < 4; ++r) dst[r*64] = pacc[r];
  }
}

// ---------------- U1 (fin fused): gi = (sum updp / (sum asum + eps)) @ Wf^T + bih ; gh = slots@Whh^T + bhh ----------------
__global__ __launch_bounds__(256) void k_u1(const float* __restrict__ updp, const float* __restrict__ asump,
                                            const float* __restrict__ slots,
                                            const float* __restrict__ Wf, const float* __restrict__ Whh,
                                            const float* __restrict__ bih, const float* __restrict__ bhh,
                                            float* __restrict__ gi, float* __restrict__ gh) {
  int cb = blockIdx.x, b = blockIdx.y, t = threadIdx.x;
  int c = cb * 256 + t;                 // 0..1535
  bool isGi = (c < 768);                // block-uniform (cb<3)
  __shared__ float X[8][256];
  __shared__ float asumS[4][8];
  if (isGi) {
    if (t < 32) {
      int h = t >> 3, kk = t & 7;
      const float* ap = asump + (size_t)(b*4 + h) * 512;
      float a = 0.f;
      #pragma unroll
      for (int s = 0; s < 64; ++s) a += ap[s*8 + kk];
      asumS[h][kk] = a + 1e-8f;
    }
    __syncthreads();
    int h = t >> 6, d = t & 63;
    const float* up = updp + (size_t)(b*4 + h) * 8192 + d;
    #pragma unroll
    for (int k = 0; k < 8; ++k) {
      float u = 0.f;
      #pragma unroll
      for (int s = 0; s < 16; ++s) u += up[s*512 + k*64];
      X[k][t] = u / asumS[h][k];
    }
  } else {
    #pragma unroll
    for (int k = 0; k < 8; ++k) X[k][t] = slots[((size_t)(b*8+k))*256 + t];
  }
  __syncthreads();
  int cc = isGi ? c : (c - 768);
  const float* Wrow = (isGi ? Wf : Whh) + (size_t)cc * 256;
  float bias = isGi ? bih[cc] : bhh[cc];
  float acc[8];
  #pragma unroll
  for (int k = 0; k < 8; ++k) acc[k] = bias;
  for (int i = 0; i < 64; ++i) {
    float4 wv = ((const float4*)Wrow)[i];
    #pragma unroll
    for (int k = 0; k < 8; ++k) {
      float4 xv = *((const float4*)&X[k][0] + i);
      acc[k] = fmaf(xv.x, wv.x, fmaf(xv.y, wv.y, fmaf(xv.z, wv.z, fmaf(xv.w, wv.w, acc[k]))));
    }
  }
  float* dst = isGi ? gi : gh;
  #pragma unroll
  for (int k = 0; k < 8; ++k) dst[((size_t)(b*8+k))*768 + cc] = acc[k];
}

// ---------------- U2: GRU + LN + MLP (+ next-iter q), 4 slots per block ----------------
__global__ __launch_bounds__(256) void k_u2(const float* __restrict__ gi, const float* __restrict__ gh,
                                            const float* __restrict__ slots_in, float* __restrict__ slots_out,
                                            const float* __restrict__ nmw, const float* __restrict__ nmb,
                                            const float* __restrict__ W1, const float* __restrict__ b1,
                                            const float* __restrict__ W2, const float* __restrict__ b2,
                                            const float* __restrict__ nsw, const float* __restrict__ nsb,
                                            const float* __restrict__ Wq, ushort_t* __restrict__ qbuf, int do_q) {
  int bid = blockIdx.x;
  int b = bid >> 1, ks0 = (bid & 1) * 4;
  int t = threadIdx.x;
  __shared__ float S[4][256];
  __shared__ float L[4][256];
  __shared__ float H1[4][256];
  // GRU
  #pragma unroll
  for (int k = 0; k < 4; ++k) {
    int slot = b*8 + ks0 + k;
    size_t gb = (size_t)slot * 768;
    float ir = gi[gb + t],        hr = gh[gb + t];
    float iz = gi[gb + 256 + t],  hz = gh[gb + 256 + t];
    float in_ = gi[gb + 512 + t], hn = gh[gb + 512 + t];
    float r = 1.f / (1.f + __expf(-(ir + hr)));
    float z = 1.f / (1.f + __expf(-(iz + hz)));
    float a = in_ + r * hn;
    float e2 = __expf(-2.f * fabsf(a));
    float nn = (1.f - e2) / (1.f + e2);
    nn = copysignf(nn, a);
    S[k][t] = (1.f - z) * nn + z * slots_in[(size_t)slot * 256 + t];
  }
  __syncthreads();
  row_ln_4x(S, L, nmw, nmb, t);
  __syncthreads();
  { // h1 = relu(L @ W1^T + b1)
    const float4* Wrow = (const float4*)(W1 + (size_t)t * 256);
    float bb = b1[t];
    float acc[4];
    #pragma unroll
    for (int k = 0; k < 4; ++k) acc[k] = bb;
    for (int i = 0; i < 64; ++i) {
      float4 wv = Wrow[i];
      #pragma unroll
      for (int k = 0; k < 4; ++k) {
        float4 xv = *((const float4*)&L[k][0] + i);
        acc[k] = fmaf(xv.x, wv.x, fmaf(xv.y, wv.y, fmaf(xv.z, wv.z, fmaf(xv.w, wv.w, acc[k]))));
      }
    }
    #pragma unroll
    for (int k = 0; k < 4; ++k) H1[k][t] = fmaxf(acc[k], 0.f);
  }
  __syncthreads();
  { // out = S + H1 @ W2^T + b2
    const float4* Wrow = (const float4*)(W2 + (size_t)t * 256);
    float bb = b2[t];
    float acc[4];
    #pragma unroll
    for (int k = 0; k < 4; ++k) acc[k] = bb;
    for (int i = 0; i < 64; ++i) {
      float4 wv = Wrow[i];
      #pragma unroll
      for (int k = 0; k < 4; ++k) {
        float4 xv = *((const float4*)&H1[k][0] + i);
        acc[k] = fmaf(xv.x, wv.x, fmaf(xv.y, wv.y, fmaf(xv.z, wv.z, fmaf(xv.w, wv.w, acc[k]))));
      }
    }
    #pragma unroll
    for (int k = 0; k < 4; ++k) {
      int slot = b*8 + ks0 + k;
      float o = S[k][t] + acc[k];
      slots_out[(size_t)slot * 256 + t] = o;
      S[k][t] = o;
    }
  }
  __syncthreads();
  if (do_q) {
    row_ln_4x(S, L, nsw, nsb, t);
    __syncthreads();
    qproj4(L, Wq, qbuf, b, ks0, t);
  }
}

// ---------------- launch ----------------
extern "C" void kernel_launch(void* const* d_in, const int* in_sizes, int n_in,
                              void* d_out, int out_size, void* d_ws, size_t ws_size,
                              hipStream_t stream) {
  (void)in_sizes; (void)n_in; (void)out_size; (void)ws_size;
  const float* x     = (const float*)d_in[0];
  const float* noise = (const float*)d_in[1];
  const float* mu    = (const float*)d_in[2];
  const float* lsig  = (const float*)d_in[3];
  const float* ninw  = (const float*)d_in[4];
  const float* ninb  = (const float*)d_in[5];
  const float* nsw   = (const float*)d_in[6];
  const float* nsb   = (const float*)d_in[7];
  const float* nmw   = (const float*)d_in[8];
  const float* nmb   = (const float*)d_in[9];
  const float* Wq    = (const float*)d_in[10];
  const float* Wk    = (const float*)d_in[11];
  const float* Wv    = (const float*)d_in[12];
  const float* Wo    = (const float*)d_in[13];
  const float* Wih   = (const float*)d_in[14];
  const float* Whh   = (const float*)d_in[15];
  const float* bih   = (const float*)d_in[16];
  const float* bhh   = (const float*)d_in[17];
  const float* W1    = (const float*)d_in[18];
  const float* b1    = (const float*)d_in[19];
  const float* W2    = (const float*)d_in[20];
  const float* b2    = (const float*)d_in[21];

  char* ws = (char*)d_ws;
  ushort_t* wkv   = (ushort_t*)(ws + 0);          //   262,144
  float*    c1    = (float*)   (ws + 262144);     //     2,048
  float*    c2    = (float*)   (ws + 264192);     //     2,048
  float*    Wf    = (float*)   (ws + 266240);     //   786,432
  float*    slots = (float*)   (ws + 1052672);    //   262,144
  ushort_t* qbuf  = (ushort_t*)(ws + 1314816);    //   262,144
  float*    gi    = (float*)   (ws + 1839104);    //   786,432
  float*    gh    = (float*)   (ws + 2625536);    //   786,432
  float*    asump = (float*)   (ws + 3411968);    //   262,144
  float*    updp  = (float*)   (ws + 3674112);    // 4,194,304
  ushort_t* kf    = (ushort_t*)(ws + 7868416);    // 67,108,864
  ushort_t* vfT   = (ushort_t*)(ws + 74977280);   // 67,108,864  (total 142,086,144)

  k_prep_wkv<<<512,  256, 0, stream>>>(Wk, Wv, ninw, ninb, wkv, c1, c2);
  k_gemm    <<<4096, 256, 0, stream>>>(x, wkv, c1, c2, kf, vfT);
  k_prep_wf <<<768,  256, 0, stream>>>(Wih, Wo, Wf);
  k_init    <<<32,   256, 0, stream>>>(noise, mu, lsig, slots, nsw, nsb, Wq, qbuf);

  float* outp = (float*)d_out;
  for (int it = 0; it < 3; ++it) {
    k_attn<<<dim3(16, 128), 256, 0, stream>>>(qbuf, kf, vfT, updp, asump);
    k_u1  <<<dim3(6, 32),   256, 0, stream>>>(updp, asump, slots, Wf, Whh, bih, bhh, gi, gh);
    k_u2  <<<64,            256, 0, stream>>>(gi, gh, slots, (it == 2) ? outp : slots,
                                              nmw, nmb, W1, b1, W2, b2, nsw, nsb, Wq, qbuf, (it < 2) ? 1 : 0);
  }
}